// Round 3
// baseline (3177.204 us; speedup 1.0000x reference)
//
#include <hip/hip_runtime.h>
#include <math.h>
#include <stdint.h>

// ---------------------------------------------------------------------------
// Earth4D hash encoding.
//   coords (N,4) f32 : lat, lon, elev, t
//   4 tables (16, 2^19, 2) f32
//   out (N, 128) f32 : [spatial 32 | xyt 32 | yzt 32 | xzt 32], level-major,
//                      F=2 features per level.
// 3 kernels: partial min/max reduce -> final reduce -> encode.
// Encode decomposition: ONE WAVE PER POINT, lane = (enc<<4)|level.
//   -> float2 store per lane = contiguous 512B per wave (coalesced)
//   -> 8 gathers per thread (512 per wave in flight, low VGPR)
// ---------------------------------------------------------------------------

constexpr int NLEV = 16;
constexpr uint32_t TSIZE = 1u << 19;
constexpr uint32_t TMASK = TSIZE - 1u;
constexpr uint32_t PRIME1 = 2654435761u;
constexpr uint32_t PRIME2 = 805459861u;

// floor(base * s^l + 0.5), s = (max/base)^(1/15), verified by hand.
// RES01[0..15] = spatial, RES01[16..31] = temporal dims 0,1
// RES2 [0..15] = spatial, RES2 [16..31] = temporal dim 2
__device__ const int RES01_TAB[32] = {
    16,20,25,32,40,51,64,81,102,128,161,203,256,323,406,512,
    8,9,10,11,12,13,14,15,17,18,20,22,24,27,29,32};
__device__ const int RES2_TAB[32] = {
    16,20,25,32,40,51,64,81,102,128,161,203,256,323,406,512,
    8,8,9,9,10,10,11,11,12,12,13,13,14,15,15,16};

__device__ __forceinline__ int imin(int a, int b) { return a < b ? a : b; }

__device__ __forceinline__ void sph(const float4 c, float& cx, float& cy, float& cz) {
  // match JAX f32 op order: r * cos(lat) * cos(lon) left-assoc
  float latr = c.x * 0.017453292519943295f;
  float lonr = c.y * 0.017453292519943295f;
  float r = 6371000.0f + c.z;
  float cl = cosf(latr), sl = sinf(latr);
  float co = cosf(lonr), so = sinf(lonr);
  float rcl = r * cl;
  cx = rcl * co;
  cy = rcl * so;
  cz = r * sl;
}

// ---------------------------------------------------------------------------
// Reduction kernels: min/max over N of (cx, cy, cz, t)
// partials layout per block: [mn0,mn1,mn2,mn3, mx0,mx1,mx2,mx3]
// ---------------------------------------------------------------------------
__global__ __launch_bounds__(256) void k_reduce1(const float4* __restrict__ coords,
                                                 int n, float* __restrict__ partials) {
  int i = blockIdx.x * 256 + threadIdx.x;
  float mn0 = INFINITY, mn1 = INFINITY, mn2 = INFINITY, mn3 = INFINITY;
  float mx0 = -INFINITY, mx1 = -INFINITY, mx2 = -INFINITY, mx3 = -INFINITY;
  if (i < n) {
    float4 c = coords[i];
    float cx, cy, cz;
    sph(c, cx, cy, cz);
    mn0 = mx0 = cx; mn1 = mx1 = cy; mn2 = mx2 = cz; mn3 = mx3 = c.w;
  }
#pragma unroll
  for (int m = 1; m < 64; m <<= 1) {
    mn0 = fminf(mn0, __shfl_xor(mn0, m));
    mn1 = fminf(mn1, __shfl_xor(mn1, m));
    mn2 = fminf(mn2, __shfl_xor(mn2, m));
    mn3 = fminf(mn3, __shfl_xor(mn3, m));
    mx0 = fmaxf(mx0, __shfl_xor(mx0, m));
    mx1 = fmaxf(mx1, __shfl_xor(mx1, m));
    mx2 = fmaxf(mx2, __shfl_xor(mx2, m));
    mx3 = fmaxf(mx3, __shfl_xor(mx3, m));
  }
  __shared__ float sred[4][8];
  int w = threadIdx.x >> 6;
  int lane = threadIdx.x & 63;
  if (lane == 0) {
    sred[w][0] = mn0; sred[w][1] = mn1; sred[w][2] = mn2; sred[w][3] = mn3;
    sred[w][4] = mx0; sred[w][5] = mx1; sred[w][6] = mx2; sred[w][7] = mx3;
  }
  __syncthreads();
  if (threadIdx.x == 0) {
    float r0 = sred[0][0], r1 = sred[0][1], r2 = sred[0][2], r3 = sred[0][3];
    float s0 = sred[0][4], s1 = sred[0][5], s2 = sred[0][6], s3 = sred[0][7];
#pragma unroll
    for (int k = 1; k < 4; ++k) {
      r0 = fminf(r0, sred[k][0]); r1 = fminf(r1, sred[k][1]);
      r2 = fminf(r2, sred[k][2]); r3 = fminf(r3, sred[k][3]);
      s0 = fmaxf(s0, sred[k][4]); s1 = fmaxf(s1, sred[k][5]);
      s2 = fmaxf(s2, sred[k][6]); s3 = fmaxf(s3, sred[k][7]);
    }
    float* p = partials + (size_t)blockIdx.x * 8;
    p[0] = r0; p[1] = r1; p[2] = r2; p[3] = r3;
    p[4] = s0; p[5] = s1; p[6] = s2; p[7] = s3;
  }
}

__global__ __launch_bounds__(256) void k_reduce2(const float* __restrict__ partials,
                                                 int nb, float* __restrict__ finals) {
  float mn0 = INFINITY, mn1 = INFINITY, mn2 = INFINITY, mn3 = INFINITY;
  float mx0 = -INFINITY, mx1 = -INFINITY, mx2 = -INFINITY, mx3 = -INFINITY;
  for (int j = threadIdx.x; j < nb; j += 256) {
    const float* p = partials + (size_t)j * 8;
    mn0 = fminf(mn0, p[0]); mn1 = fminf(mn1, p[1]);
    mn2 = fminf(mn2, p[2]); mn3 = fminf(mn3, p[3]);
    mx0 = fmaxf(mx0, p[4]); mx1 = fmaxf(mx1, p[5]);
    mx2 = fmaxf(mx2, p[6]); mx3 = fmaxf(mx3, p[7]);
  }
#pragma unroll
  for (int m = 1; m < 64; m <<= 1) {
    mn0 = fminf(mn0, __shfl_xor(mn0, m));
    mn1 = fminf(mn1, __shfl_xor(mn1, m));
    mn2 = fminf(mn2, __shfl_xor(mn2, m));
    mn3 = fminf(mn3, __shfl_xor(mn3, m));
    mx0 = fmaxf(mx0, __shfl_xor(mx0, m));
    mx1 = fmaxf(mx1, __shfl_xor(mx1, m));
    mx2 = fmaxf(mx2, __shfl_xor(mx2, m));
    mx3 = fmaxf(mx3, __shfl_xor(mx3, m));
  }
  __shared__ float sred[4][8];
  int w = threadIdx.x >> 6;
  int lane = threadIdx.x & 63;
  if (lane == 0) {
    sred[w][0] = mn0; sred[w][1] = mn1; sred[w][2] = mn2; sred[w][3] = mn3;
    sred[w][4] = mx0; sred[w][5] = mx1; sred[w][6] = mx2; sred[w][7] = mx3;
  }
  __syncthreads();
  if (threadIdx.x == 0) {
    float r0 = sred[0][0], r1 = sred[0][1], r2 = sred[0][2], r3 = sred[0][3];
    float s0 = sred[0][4], s1 = sred[0][5], s2 = sred[0][6], s3 = sred[0][7];
#pragma unroll
    for (int k = 1; k < 4; ++k) {
      r0 = fminf(r0, sred[k][0]); r1 = fminf(r1, sred[k][1]);
      r2 = fminf(r2, sred[k][2]); r3 = fminf(r3, sred[k][3]);
      s0 = fmaxf(s0, sred[k][4]); s1 = fmaxf(s1, sred[k][5]);
      s2 = fmaxf(s2, sred[k][6]); s3 = fmaxf(s3, sred[k][7]);
    }
    finals[0] = r0; finals[1] = r1; finals[2] = r2; finals[3] = r3;
    finals[4] = s0; finals[5] = s1; finals[6] = s2; finals[7] = s3;
  }
}

// ---------------------------------------------------------------------------
// Encode: one WAVE per point. lane = enc*16 + level.
//   enc 0: (x,y,z) spatial res     enc 1: (x,y,t)
//   enc 2: (y,z,t)                 enc 3: (x,z,t)   temporal res
// Output offset for lane l: pt*128 + l*2  (enc*32 + level*2 == l*2).
// ---------------------------------------------------------------------------
__global__ __launch_bounds__(256) void k_encode(const float4* __restrict__ coords,
                                                const float* __restrict__ t_xyz,
                                                const float* __restrict__ t_xyt,
                                                const float* __restrict__ t_yzt,
                                                const float* __restrict__ t_xzt,
                                                const float* __restrict__ finals,
                                                float* __restrict__ out, int n) {
  int gid = blockIdx.x * 256 + threadIdx.x;
  int pt = gid >> 6;
  int lane = gid & 63;
  if (pt >= n) return;

  float4 c = coords[pt];  // same address across wave -> broadcast
  float cx, cy, cz;
  sph(c, cx, cy, cz);

  float mn0 = finals[0], mn1 = finals[1], mn2 = finals[2], mn3 = finals[3];
  float mx0 = finals[4], mx1 = finals[5], mx2 = finals[6], mx3 = finals[7];

  float sx = (cx - mn0) / (mx0 - mn0);
  float sy = (cy - mn1) / (mx1 - mn1);
  float sz = (cz - mn2) / (mx2 - mn2);
  float tn = (c.w - mn3) / (mx3 - mn3);
  float ts = (tn * 2.0f - 1.0f) * 0.9f;

  // hash_encode's own normalization: clip((v+1)/2, 0, 1)
  float xsx = fminf(fmaxf((sx + 1.0f) * 0.5f, 0.0f), 1.0f);
  float xsy = fminf(fmaxf((sy + 1.0f) * 0.5f, 0.0f), 1.0f);
  float xsz = fminf(fmaxf((sz + 1.0f) * 0.5f, 0.0f), 1.0f);
  float xst = fminf(fmaxf((ts + 1.0f) * 0.5f, 0.0f), 1.0f);

  int enc = lane >> 4;
  int lev = lane & 15;

  // coordinate selection per encoding
  float x0 = (enc == 2) ? xsy : xsx;
  float x1 = (enc <= 1) ? xsy : xsz;
  float x2 = (enc == 0) ? xsz : xst;

  const float* tab = (enc == 0) ? t_xyz
                   : (enc == 1) ? t_xyt
                   : (enc == 2) ? t_yzt : t_xzt;

  int ridx = ((enc != 0) << 4) | lev;
  int r01 = RES01_TAB[ridx];
  int r2  = RES2_TAB[ridx];

  float p0 = x0 * (float)(r01 - 1);
  float p1 = x1 * (float)(r01 - 1);
  float p2 = x2 * (float)(r2 - 1);
  float f0 = floorf(p0), f1 = floorf(p1), f2 = floorf(p2);
  float w0 = p0 - f0, w1 = p1 - f1, w2 = p2 - f2;
  int i0 = (int)f0, i1 = (int)f1, i2 = (int)f2;

  uint32_t hx0 = (uint32_t)i0;                       // prime = 1
  uint32_t hx1 = (uint32_t)imin(i0 + 1, r01 - 1);
  uint32_t hy0 = (uint32_t)i1 * PRIME1;
  uint32_t hy1 = (uint32_t)imin(i1 + 1, r01 - 1) * PRIME1;
  uint32_t hz0 = (uint32_t)i2 * PRIME2;
  uint32_t hz1 = (uint32_t)imin(i2 + 1, r2 - 1) * PRIME2;

  float wx0 = 1.0f - w0, wy0 = 1.0f - w1, wz0 = 1.0f - w2;
  const float* tb = tab + (size_t)lev * (TSIZE * 2);

  // compute all indices first, then issue all 8 gathers, then accumulate
  uint32_t idxs[8];
  float wcs[8];
#pragma unroll
  for (int cc = 0; cc < 8; ++cc) {
    uint32_t hx = (cc & 1) ? hx1 : hx0;
    uint32_t hy = (cc & 2) ? hy1 : hy0;
    uint32_t hz = (cc & 4) ? hz1 : hz0;
    idxs[cc] = (hx ^ hy ^ hz) & TMASK;
    wcs[cc] = ((cc & 1) ? w0 : wx0) * ((cc & 2) ? w1 : wy0) * ((cc & 4) ? w2 : wz0);
  }
  float2 tv[8];
#pragma unroll
  for (int cc = 0; cc < 8; ++cc)
    tv[cc] = *reinterpret_cast<const float2*>(tb + (size_t)idxs[cc] * 2u);

  float a0 = 0.0f, a1 = 0.0f;
#pragma unroll
  for (int cc = 0; cc < 8; ++cc) {
    a0 += tv[cc].x * wcs[cc];
    a1 += tv[cc].y * wcs[cc];
  }

  *reinterpret_cast<float2*>(out + (size_t)pt * 128 + lane * 2) = make_float2(a0, a1);
}

// ---------------------------------------------------------------------------
extern "C" void kernel_launch(void* const* d_in, const int* in_sizes, int n_in,
                              void* d_out, int out_size, void* d_ws, size_t ws_size,
                              hipStream_t stream) {
  const float4* coords = (const float4*)d_in[0];
  const float* t_xyz = (const float*)d_in[1];
  const float* t_xyt = (const float*)d_in[2];
  const float* t_yzt = (const float*)d_in[3];
  const float* t_xzt = (const float*)d_in[4];
  float* out = (float*)d_out;

  int n = in_sizes[0] / 4;
  int nb = (n + 255) / 256;

  float* partials = (float*)d_ws;               // nb*8 floats
  float* finals = partials + (size_t)nb * 8;    // 8 floats

  k_reduce1<<<nb, 256, 0, stream>>>(coords, n, partials);
  k_reduce2<<<1, 256, 0, stream>>>(partials, nb, finals);

  long long total = (long long)n * 64;
  int nb_enc = (int)((total + 255) / 256);
  k_encode<<<nb_enc, 256, 0, stream>>>(coords, t_xyz, t_xyt, t_yzt, t_xzt, finals, out, n);
}

// Round 4
// 1120.732 us; speedup vs baseline: 2.8349x; 2.8349x over previous
//
#include <hip/hip_runtime.h>
#include <math.h>
#include <stdint.h>

// ---------------------------------------------------------------------------
// Earth4D hash encoding.
//   coords (N,4) f32 : lat, lon, elev, t
//   4 tables (16, 2^19, 2) f32
//   out (N, 128) f32
// Kernels: minmax reduce x2 -> dehash (dense copy of small levels) -> encode.
// Encode: ONE WAVE PER POINT, lane = (enc<<4)|level.
// Dense de-hash: temporal tables (all 16 levels, 77756 f2 each) and spatial
// levels 0-6 (519284 f2) copied into d_ws as dense [z][y][x] grids so corner
// gathers share cache lines and hot sets shrink 8x.
// ---------------------------------------------------------------------------

constexpr int NLEV = 16;
constexpr uint32_t TSIZE = 1u << 19;
constexpr uint32_t TMASK = TSIZE - 1u;
constexpr uint32_t PRIME1 = 2654435761u;
constexpr uint32_t PRIME2 = 805459861u;

constexpr int SP_DENSE_LEVELS = 7;      // spatial levels 0..6 dense (res<=64)
constexpr int TD_BASE = 519284;         // float2 offset of temporal dense region
constexpr int TT_STRIDE = 77756;        // float2 per temporal table
constexpr size_t DENSE_F2 = 752552;     // total dense float2 entries

// resolutions: floor(base*s^l+0.5)
__device__ const int RES01_TAB[32] = {
    16,20,25,32,40,51,64,81,102,128,161,203,256,323,406,512,
    8,9,10,11,12,13,14,15,17,18,20,22,24,27,29,32};
__device__ const int RES2_TAB[32] = {
    16,20,25,32,40,51,64,81,102,128,161,203,256,323,406,512,
    8,8,9,9,10,10,11,11,12,12,13,13,14,15,15,16};

// dense offsets (float2 units)
__device__ const int SP_DOFF[7] = {0,4096,12096,27721,60489,124489,257140};
__device__ const int T_DOFF[16] = {0,512,1160,2060,3149,4589,6279,8435,
                                   10910,14378,18266,23466,29758,37822,48757,61372};

// prep-kernel segment metadata: 7 spatial + 48 temporal = 55 segments
__device__ const int SEG_DST[55] = {
  0,4096,12096,27721,60489,124489,257140,
  // table1 (xyt)
  519284+0,519284+512,519284+1160,519284+2060,519284+3149,519284+4589,519284+6279,519284+8435,
  519284+10910,519284+14378,519284+18266,519284+23466,519284+29758,519284+37822,519284+48757,519284+61372,
  // table2 (yzt)
  597040+0,597040+512,597040+1160,597040+2060,597040+3149,597040+4589,597040+6279,597040+8435,
  597040+10910,597040+14378,597040+18266,597040+23466,597040+29758,597040+37822,597040+48757,597040+61372,
  // table3 (xzt)
  674796+0,674796+512,674796+1160,674796+2060,674796+3149,674796+4589,674796+6279,674796+8435,
  674796+10910,674796+14378,674796+18266,674796+23466,674796+29758,674796+37822,674796+48757,674796+61372};
__device__ const int SEG_TAB[55] = {
  0,0,0,0,0,0,0,
  1,1,1,1,1,1,1,1,1,1,1,1,1,1,1,1,
  2,2,2,2,2,2,2,2,2,2,2,2,2,2,2,2,
  3,3,3,3,3,3,3,3,3,3,3,3,3,3,3,3};
__device__ const int SEG_LEV[55] = {
  0,1,2,3,4,5,6,
  0,1,2,3,4,5,6,7,8,9,10,11,12,13,14,15,
  0,1,2,3,4,5,6,7,8,9,10,11,12,13,14,15,
  0,1,2,3,4,5,6,7,8,9,10,11,12,13,14,15};
__device__ const int SEG_R01[55] = {
  16,20,25,32,40,51,64,
  8,9,10,11,12,13,14,15,17,18,20,22,24,27,29,32,
  8,9,10,11,12,13,14,15,17,18,20,22,24,27,29,32,
  8,9,10,11,12,13,14,15,17,18,20,22,24,27,29,32};
__device__ const int SEG_R2[55] = {
  16,20,25,32,40,51,64,
  8,8,9,9,10,10,11,11,12,12,13,13,14,15,15,16,
  8,8,9,9,10,10,11,11,12,12,13,13,14,15,15,16,
  8,8,9,9,10,10,11,11,12,12,13,13,14,15,15,16};
__device__ const int SEG_SIZE[55] = {
  4096,8000,15625,32768,64000,132651,262144,
  512,648,900,1089,1440,1690,2156,2475,3468,3888,5200,6292,8064,10935,12615,16384,
  512,648,900,1089,1440,1690,2156,2475,3468,3888,5200,6292,8064,10935,12615,16384,
  512,648,900,1089,1440,1690,2156,2475,3468,3888,5200,6292,8064,10935,12615,16384};

__device__ __forceinline__ int imin(int a, int b) { return a < b ? a : b; }

__device__ __forceinline__ void sph(const float4 c, float& cx, float& cy, float& cz) {
  float latr = c.x * 0.017453292519943295f;
  float lonr = c.y * 0.017453292519943295f;
  float r = 6371000.0f + c.z;
  float cl = cosf(latr), sl = sinf(latr);
  float co = cosf(lonr), so = sinf(lonr);
  float rcl = r * cl;
  cx = rcl * co;
  cy = rcl * so;
  cz = r * sl;
}

// ---------------------------------------------------------------------------
// min/max reduction (exact, order-independent)
// ---------------------------------------------------------------------------
__global__ __launch_bounds__(256) void k_reduce1(const float4* __restrict__ coords,
                                                 int n, float* __restrict__ partials) {
  int i = blockIdx.x * 256 + threadIdx.x;
  float mn0 = INFINITY, mn1 = INFINITY, mn2 = INFINITY, mn3 = INFINITY;
  float mx0 = -INFINITY, mx1 = -INFINITY, mx2 = -INFINITY, mx3 = -INFINITY;
  if (i < n) {
    float4 c = coords[i];
    float cx, cy, cz;
    sph(c, cx, cy, cz);
    mn0 = mx0 = cx; mn1 = mx1 = cy; mn2 = mx2 = cz; mn3 = mx3 = c.w;
  }
#pragma unroll
  for (int m = 1; m < 64; m <<= 1) {
    mn0 = fminf(mn0, __shfl_xor(mn0, m));
    mn1 = fminf(mn1, __shfl_xor(mn1, m));
    mn2 = fminf(mn2, __shfl_xor(mn2, m));
    mn3 = fminf(mn3, __shfl_xor(mn3, m));
    mx0 = fmaxf(mx0, __shfl_xor(mx0, m));
    mx1 = fmaxf(mx1, __shfl_xor(mx1, m));
    mx2 = fmaxf(mx2, __shfl_xor(mx2, m));
    mx3 = fmaxf(mx3, __shfl_xor(mx3, m));
  }
  __shared__ float sred[4][8];
  int w = threadIdx.x >> 6;
  int lane = threadIdx.x & 63;
  if (lane == 0) {
    sred[w][0] = mn0; sred[w][1] = mn1; sred[w][2] = mn2; sred[w][3] = mn3;
    sred[w][4] = mx0; sred[w][5] = mx1; sred[w][6] = mx2; sred[w][7] = mx3;
  }
  __syncthreads();
  if (threadIdx.x == 0) {
    float r0 = sred[0][0], r1 = sred[0][1], r2 = sred[0][2], r3 = sred[0][3];
    float s0 = sred[0][4], s1 = sred[0][5], s2 = sred[0][6], s3 = sred[0][7];
#pragma unroll
    for (int k = 1; k < 4; ++k) {
      r0 = fminf(r0, sred[k][0]); r1 = fminf(r1, sred[k][1]);
      r2 = fminf(r2, sred[k][2]); r3 = fminf(r3, sred[k][3]);
      s0 = fmaxf(s0, sred[k][4]); s1 = fmaxf(s1, sred[k][5]);
      s2 = fmaxf(s2, sred[k][6]); s3 = fmaxf(s3, sred[k][7]);
    }
    float* p = partials + (size_t)blockIdx.x * 8;
    p[0] = r0; p[1] = r1; p[2] = r2; p[3] = r3;
    p[4] = s0; p[5] = s1; p[6] = s2; p[7] = s3;
  }
}

__global__ __launch_bounds__(256) void k_reduce2(const float* __restrict__ partials,
                                                 int nb, float* __restrict__ finals) {
  float mn0 = INFINITY, mn1 = INFINITY, mn2 = INFINITY, mn3 = INFINITY;
  float mx0 = -INFINITY, mx1 = -INFINITY, mx2 = -INFINITY, mx3 = -INFINITY;
  for (int j = threadIdx.x; j < nb; j += 256) {
    const float* p = partials + (size_t)j * 8;
    mn0 = fminf(mn0, p[0]); mn1 = fminf(mn1, p[1]);
    mn2 = fminf(mn2, p[2]); mn3 = fminf(mn3, p[3]);
    mx0 = fmaxf(mx0, p[4]); mx1 = fmaxf(mx1, p[5]);
    mx2 = fmaxf(mx2, p[6]); mx3 = fmaxf(mx3, p[7]);
  }
#pragma unroll
  for (int m = 1; m < 64; m <<= 1) {
    mn0 = fminf(mn0, __shfl_xor(mn0, m));
    mn1 = fminf(mn1, __shfl_xor(mn1, m));
    mn2 = fminf(mn2, __shfl_xor(mn2, m));
    mn3 = fminf(mn3, __shfl_xor(mn3, m));
    mx0 = fmaxf(mx0, __shfl_xor(mx0, m));
    mx1 = fmaxf(mx1, __shfl_xor(mx1, m));
    mx2 = fmaxf(mx2, __shfl_xor(mx2, m));
    mx3 = fmaxf(mx3, __shfl_xor(mx3, m));
  }
  __shared__ float sred[4][8];
  int w = threadIdx.x >> 6;
  int lane = threadIdx.x & 63;
  if (lane == 0) {
    sred[w][0] = mn0; sred[w][1] = mn1; sred[w][2] = mn2; sred[w][3] = mn3;
    sred[w][4] = mx0; sred[w][5] = mx1; sred[w][6] = mx2; sred[w][7] = mx3;
  }
  __syncthreads();
  if (threadIdx.x == 0) {
    float r0 = sred[0][0], r1 = sred[0][1], r2 = sred[0][2], r3 = sred[0][3];
    float s0 = sred[0][4], s1 = sred[0][5], s2 = sred[0][6], s3 = sred[0][7];
#pragma unroll
    for (int k = 1; k < 4; ++k) {
      r0 = fminf(r0, sred[k][0]); r1 = fminf(r1, sred[k][1]);
      r2 = fminf(r2, sred[k][2]); r3 = fminf(r3, sred[k][3]);
      s0 = fmaxf(s0, sred[k][4]); s1 = fmaxf(s1, sred[k][5]);
      s2 = fmaxf(s2, sred[k][6]); s3 = fmaxf(s3, sred[k][7]);
    }
    finals[0] = r0; finals[1] = r1; finals[2] = r2; finals[3] = r3;
    finals[4] = s0; finals[5] = s1; finals[6] = s2; finals[7] = s3;
  }
}

// ---------------------------------------------------------------------------
// De-hash: copy small levels into dense [z][y][x] grids (x fastest).
// grid = (1024, 55); segments smaller than 1024 blocks exit early.
// ---------------------------------------------------------------------------
__global__ __launch_bounds__(256) void k_dehash(const float* __restrict__ t_xyz,
                                                const float* __restrict__ t_xyt,
                                                const float* __restrict__ t_yzt,
                                                const float* __restrict__ t_xzt,
                                                float* __restrict__ dense) {
  int seg = blockIdx.y;
  int sz = SEG_SIZE[seg];
  int e = blockIdx.x * 256 + threadIdx.x;
  if (e >= sz) return;
  int r01 = SEG_R01[seg];
  int x = e % r01;
  int rem = e / r01;
  int y = rem % r01;
  int z = rem / r01;
  uint32_t h = ((uint32_t)x ^ ((uint32_t)y * PRIME1) ^ ((uint32_t)z * PRIME2)) & TMASK;
  int tb = SEG_TAB[seg];
  const float* src = (tb == 0) ? t_xyz : (tb == 1) ? t_xyt : (tb == 2) ? t_yzt : t_xzt;
  src += (size_t)SEG_LEV[seg] * (TSIZE * 2);
  const float2 v = *reinterpret_cast<const float2*>(src + (size_t)h * 2u);
  *reinterpret_cast<float2*>(dense + ((size_t)SEG_DST[seg] + e) * 2u) = v;
}

// ---------------------------------------------------------------------------
// Encode: one WAVE per point. lane = enc*16 + level.
// use_dense: lanes with small index domains read the dense grids.
// ---------------------------------------------------------------------------
__global__ __launch_bounds__(256) void k_encode(const float4* __restrict__ coords,
                                                const float* __restrict__ t_xyz,
                                                const float* __restrict__ t_xyt,
                                                const float* __restrict__ t_yzt,
                                                const float* __restrict__ t_xzt,
                                                const float* __restrict__ dense,
                                                const float* __restrict__ finals,
                                                float* __restrict__ out, int n,
                                                int use_dense) {
  int gid = blockIdx.x * 256 + threadIdx.x;
  int pt = gid >> 6;
  int lane = gid & 63;
  if (pt >= n) return;

  float4 c = coords[pt];  // wave-uniform -> broadcast
  float cx, cy, cz;
  sph(c, cx, cy, cz);

  float mn0 = finals[0], mn1 = finals[1], mn2 = finals[2], mn3 = finals[3];
  float mx0 = finals[4], mx1 = finals[5], mx2 = finals[6], mx3 = finals[7];

  float sx = (cx - mn0) / (mx0 - mn0);
  float sy = (cy - mn1) / (mx1 - mn1);
  float sz = (cz - mn2) / (mx2 - mn2);
  float tn = (c.w - mn3) / (mx3 - mn3);
  float ts = (tn * 2.0f - 1.0f) * 0.9f;

  float xsx = fminf(fmaxf((sx + 1.0f) * 0.5f, 0.0f), 1.0f);
  float xsy = fminf(fmaxf((sy + 1.0f) * 0.5f, 0.0f), 1.0f);
  float xsz = fminf(fmaxf((sz + 1.0f) * 0.5f, 0.0f), 1.0f);
  float xst = fminf(fmaxf((ts + 1.0f) * 0.5f, 0.0f), 1.0f);

  int enc = lane >> 4;
  int lev = lane & 15;

  float x0f = (enc == 2) ? xsy : xsx;
  float x1f = (enc <= 1) ? xsy : xsz;
  float x2f = (enc == 0) ? xsz : xst;

  int ridx = ((enc != 0) << 4) | lev;
  int r01 = RES01_TAB[ridx];
  int r2  = RES2_TAB[ridx];

  float p0 = x0f * (float)(r01 - 1);
  float p1 = x1f * (float)(r01 - 1);
  float p2 = x2f * (float)(r2 - 1);
  float f0 = floorf(p0), f1 = floorf(p1), f2 = floorf(p2);
  float w0 = p0 - f0, w1 = p1 - f1, w2 = p2 - f2;
  int i0 = (int)f0, i1 = (int)f1, i2 = (int)f2;

  int x0 = i0, x1 = imin(i0 + 1, r01 - 1);
  int y0 = i1, y1 = imin(i1 + 1, r01 - 1);
  int z0 = i2, z1 = imin(i2 + 1, r2 - 1);

  float wx0 = 1.0f - w0, wy0 = 1.0f - w1, wz0 = 1.0f - w2;

  uint32_t idxs[8];
  const float* base;
  bool isdense = use_dense && (enc != 0 || lev < SP_DENSE_LEVELS);
  if (isdense) {
    int off = (enc == 0) ? SP_DOFF[lev] : (TD_BASE + (enc - 1) * TT_STRIDE + T_DOFF[lev]);
    int zr0 = z0 * r01, zr1 = z1 * r01;
#pragma unroll
    for (int cc = 0; cc < 8; ++cc) {
      int xc = (cc & 1) ? x1 : x0;
      int yc = (cc & 2) ? y1 : y0;
      int zr = (cc & 4) ? zr1 : zr0;
      idxs[cc] = (uint32_t)(off + (zr + yc) * r01 + xc);
    }
    base = dense;
  } else {
    uint32_t hx0 = (uint32_t)x0, hx1 = (uint32_t)x1;
    uint32_t hy0 = (uint32_t)y0 * PRIME1, hy1 = (uint32_t)y1 * PRIME1;
    uint32_t hz0 = (uint32_t)z0 * PRIME2, hz1 = (uint32_t)z1 * PRIME2;
#pragma unroll
    for (int cc = 0; cc < 8; ++cc) {
      uint32_t hx = (cc & 1) ? hx1 : hx0;
      uint32_t hy = (cc & 2) ? hy1 : hy0;
      uint32_t hz = (cc & 4) ? hz1 : hz0;
      idxs[cc] = (hx ^ hy ^ hz) & TMASK;
    }
    const float* tab = (enc == 0) ? t_xyz
                     : (enc == 1) ? t_xyt
                     : (enc == 2) ? t_yzt : t_xzt;
    base = tab + (size_t)lev * (TSIZE * 2);
  }

  float wcs[8];
#pragma unroll
  for (int cc = 0; cc < 8; ++cc)
    wcs[cc] = ((cc & 1) ? w0 : wx0) * ((cc & 2) ? w1 : wy0) * ((cc & 4) ? w2 : wz0);

  float2 tv[8];
#pragma unroll
  for (int cc = 0; cc < 8; ++cc)
    tv[cc] = *reinterpret_cast<const float2*>(base + (size_t)idxs[cc] * 2u);

  float a0 = 0.0f, a1 = 0.0f;
#pragma unroll
  for (int cc = 0; cc < 8; ++cc) {
    a0 += tv[cc].x * wcs[cc];
    a1 += tv[cc].y * wcs[cc];
  }

  *reinterpret_cast<float2*>(out + (size_t)pt * 128 + lane * 2) = make_float2(a0, a1);
}

// ---------------------------------------------------------------------------
extern "C" void kernel_launch(void* const* d_in, const int* in_sizes, int n_in,
                              void* d_out, int out_size, void* d_ws, size_t ws_size,
                              hipStream_t stream) {
  const float4* coords = (const float4*)d_in[0];
  const float* t_xyz = (const float*)d_in[1];
  const float* t_xyt = (const float*)d_in[2];
  const float* t_yzt = (const float*)d_in[3];
  const float* t_xzt = (const float*)d_in[4];
  float* out = (float*)d_out;

  int n = in_sizes[0] / 4;
  int nb = (n + 255) / 256;

  size_t dense_bytes = DENSE_F2 * 8;                       // 6,020,416
  size_t part_off = (dense_bytes + 255) & ~(size_t)255;
  size_t need = part_off + (size_t)nb * 8 * 4 + 32;
  int use_dense = (ws_size >= need) ? 1 : 0;

  float* dense = (float*)d_ws;
  float* partials = (float*)((char*)d_ws + (use_dense ? part_off : 0));
  float* finals = partials + (size_t)nb * 8;

  k_reduce1<<<nb, 256, 0, stream>>>(coords, n, partials);
  k_reduce2<<<1, 256, 0, stream>>>(partials, nb, finals);
  if (use_dense) {
    dim3 grid(1024, 55);
    k_dehash<<<grid, 256, 0, stream>>>(t_xyz, t_xyt, t_yzt, t_xzt, dense);
  }

  long long total = (long long)n * 64;
  int nb_enc = (int)((total + 255) / 256);
  k_encode<<<nb_enc, 256, 0, stream>>>(coords, t_xyz, t_xyt, t_yzt, t_xzt,
                                       dense, finals, out, n, use_dense);
}